// Round 2
// baseline (1032.100 us; speedup 1.0000x reference)
//
#include <hip/hip_runtime.h>
#include <math.h>

#define BB 4
#define TT 2048
#define EE 1024
#define HH 16
#define DD 64
#define MM (BB*TT)   // 8192 tokens

typedef unsigned short u16;
typedef __bf16 bf16x8 __attribute__((ext_vector_type(8)));
typedef float  f32x4  __attribute__((ext_vector_type(4)));

__device__ inline float bf2f(u16 u){ union{unsigned int i; float f;} v; v.i=((unsigned int)u)<<16; return v.f; }
__device__ inline u16 f2bf(float f){ union{float f; unsigned int i;} v; v.f=f; return (u16)((v.i + 0x7fffu + ((v.i>>16)&1u))>>16); }

__device__ inline void gload_lds16(const void* g, void* l){
  __builtin_amdgcn_global_load_lds((__attribute__((address_space(1))) void*)g,
                                   (__attribute__((address_space(3))) void*)l, 16, 0, 0);
}

// ---------------- tiled transpose f32 -> bf16: W[K][N] -> WT[N][K] ----------------
__global__ __launch_bounds__(256) void transpose_tile(
    const float* __restrict__ W, u16* __restrict__ WT, int N, int K)
{
    __shared__ float t[32][33];
    const int n0 = blockIdx.x*32, k0 = blockIdx.y*32;
    const int tx = threadIdx.x, ty = threadIdx.y;   // 32 x 8
    #pragma unroll
    for (int j=0;j<4;j++)
        t[ty + j*8][tx] = W[(size_t)(k0 + ty + j*8)*N + n0 + tx];
    __syncthreads();
    #pragma unroll
    for (int j=0;j<4;j++)
        WT[(size_t)(n0 + ty + j*8)*K + k0 + tx] = f2bf(t[tx][ty + j*8]);
}

// ---------------- QKV repack f32 -> bf16 ----------------
// WqkvT [3072][1024]: row n = which*1024 + h*64 + d, col c = value w{q,k,v}[h][c][d]
__global__ __launch_bounds__(256) void repack_qkv_tiled(
    const float* __restrict__ wq, const float* __restrict__ wk, const float* __restrict__ wv,
    u16* __restrict__ WT)
{
    __shared__ float t[32][33];
    const int z = blockIdx.z, which = z>>4, hh = z&15;
    const int d0 = blockIdx.x*32, c0 = blockIdx.y*32;
    const int tx = threadIdx.x, ty = threadIdx.y;
    const float* w = which==0 ? wq : (which==1 ? wk : wv);
    #pragma unroll
    for (int j=0;j<4;j++)
        t[ty + j*8][tx] = w[((size_t)hh*EE + c0 + ty + j*8)*DD + d0 + tx];
    __syncthreads();
    #pragma unroll
    for (int j=0;j<4;j++)
        WT[(size_t)(which*1024 + hh*64 + d0 + ty + j*8)*1024 + c0 + tx] = f2bf(t[tx][ty + j*8]);
}

__global__ __launch_bounds__(256) void copy_bias_qkv(
    const float* __restrict__ bq, const float* __restrict__ bk, const float* __restrict__ bv,
    float* __restrict__ bias)
{
    int i = blockIdx.x*256 + threadIdx.x;   // < 3072
    const float* b = i<1024 ? bq : (i<2048 ? bk : bv);
    bias[i] = b[i & 1023];
}

// ---------------- embed + LN1 (f32 in; x f32 out, h bf16 out) ----------------
__global__ __launch_bounds__(256) void embed_ln1(
    const int* __restrict__ ids, const float* __restrict__ wte, const float* __restrict__ wpe,
    const float* __restrict__ g, const float* __restrict__ b,
    float* __restrict__ x_out, u16* __restrict__ h_out)
{
    const int token = blockIdx.x;
    const int t = token & (TT-1);
    const int id = ids[token];
    const int tid = threadIdx.x;
    float vals[4]; float s=0.f, s2=0.f;
    #pragma unroll
    for (int i=0;i<4;i++){
        int e = tid + i*256;
        float v = wte[(size_t)id*EE + e] + wpe[(size_t)t*EE + e];
        vals[i]=v; s+=v; s2+=v*v;
    }
    for (int off=32; off>=1; off>>=1){ s += __shfl_xor(s,off); s2 += __shfl_xor(s2,off); }
    __shared__ float red[8];
    int wave=tid>>6, lane=tid&63;
    if (lane==0){ red[wave]=s; red[4+wave]=s2; }
    __syncthreads();
    s = red[0]+red[1]+red[2]+red[3];
    s2 = red[4]+red[5]+red[6]+red[7];
    float mu = s*(1.f/EE);
    float var = s2*(1.f/EE) - mu*mu;
    float rstd = rsqrtf(var + 1e-5f);
    #pragma unroll
    for (int i=0;i<4;i++){
        int e = tid + i*256; float v = vals[i];
        x_out[(size_t)token*EE + e] = v;
        h_out[(size_t)token*EE + e] = f2bf((v-mu)*rstd*g[e] + b[e]);
    }
}

// ---------------- LN2 (f32 in, bf16 out) ----------------
__global__ __launch_bounds__(256) void ln_fwd(
    const float* __restrict__ xin, const float* __restrict__ g, const float* __restrict__ b,
    u16* __restrict__ hout)
{
    const int token = blockIdx.x;
    const int tid = threadIdx.x;
    float vals[4]; float s=0.f, s2=0.f;
    #pragma unroll
    for (int i=0;i<4;i++){
        int e = tid + i*256;
        float v = xin[(size_t)token*EE + e];
        vals[i]=v; s+=v; s2+=v*v;
    }
    for (int off=32; off>=1; off>>=1){ s += __shfl_xor(s,off); s2 += __shfl_xor(s2,off); }
    __shared__ float red[8];
    int wave=tid>>6, lane=tid&63;
    if (lane==0){ red[wave]=s; red[4+wave]=s2; }
    __syncthreads();
    s = red[0]+red[1]+red[2]+red[3];
    s2 = red[4]+red[5]+red[6]+red[7];
    float mu = s*(1.f/EE);
    float var = s2*(1.f/EE) - mu*mu;
    float rstd = rsqrtf(var + 1e-5f);
    #pragma unroll
    for (int i=0;i<4;i++){
        int e = tid + i*256; float v = vals[i];
        hout[(size_t)token*EE + e] = f2bf((v-mu)*rstd*g[e] + b[e]);
    }
}

// ---------------- GEMM: C = A[M,K](bf16) * BT[N,K]^T(bf16) + bias(f32) ----------------
// MODE 0: scatter bf16 to Q/K/V [B,H,T,D]
// MODE 1: CoutF = resid + v   (f32, may alias resid)
// MODE 2: CoutH = gelu(v)     (bf16)
template<int MODE>
__global__ __launch_bounds__(256) void gemm_bt(
    const u16* __restrict__ A, const u16* __restrict__ BT, const float* __restrict__ bias,
    float* CoutF, const float* resid, u16* __restrict__ CoutH,
    u16* __restrict__ q_out, u16* __restrict__ k_out, u16* __restrict__ v_out,
    int Ndim, int Kdim)
{
    __shared__ u16 As[128*32];
    __shared__ u16 Bs[128*32];
    const int tid = threadIdx.x, wave = tid>>6, lane = tid&63;
    const int quad = lane>>4, l16 = lane&15;
    const int m0 = blockIdx.x<<7, n0 = blockIdx.y<<7;
    const int wm = (wave>>1)<<6, wn = (wave&1)<<6;
    const f32x4 zf = {0.f,0.f,0.f,0.f};
    f32x4 acc[4][4];
    #pragma unroll
    for (int i=0;i<4;i++)
        #pragma unroll
        for (int j=0;j<4;j++) acc[i][j]=zf;

    const int rA = lane>>2;        // row within 16-row group
    const int kA = (lane&3)*8;     // element offset along k
    for (int k0=0; k0<Kdim; k0+=32){
        __syncthreads();
        #pragma unroll
        for (int i=0;i<2;i++){
            const int inst = wave*2+i;
            const int row  = inst*16 + rA;
            gload_lds16(A  + (size_t)(m0+row)*Kdim + k0 + kA, &As[inst*512]);
            gload_lds16(BT + (size_t)(n0+row)*Kdim + k0 + kA, &Bs[inst*512]);
        }
        __syncthreads();
        bf16x8 af[4], bfr[4];
        #pragma unroll
        for (int mt=0;mt<4;mt++) af[mt]  = *(const bf16x8*)&As[(wm + mt*16 + l16)*32 + quad*8];
        #pragma unroll
        for (int nt=0;nt<4;nt++) bfr[nt] = *(const bf16x8*)&Bs[(wn + nt*16 + l16)*32 + quad*8];
        #pragma unroll
        for (int mt=0;mt<4;mt++)
            #pragma unroll
            for (int nt=0;nt<4;nt++)
                acc[mt][nt] = __builtin_amdgcn_mfma_f32_16x16x32_bf16(af[mt], bfr[nt], acc[mt][nt], 0, 0, 0);
    }
    // epilogue
    #pragma unroll
    for (int mt=0;mt<4;mt++){
        #pragma unroll
        for (int nt=0;nt<4;nt++){
            #pragma unroll
            for (int r=0;r<4;r++){
                int m = m0 + wm + mt*16 + quad*4 + r;
                int n = n0 + wn + nt*16 + l16;
                float v = acc[mt][nt][r] + bias[n];
                if (MODE==0){
                    int which = n>>10, hd = n&1023, hh = hd>>6, d = hd&63;
                    u16* dst = which==0 ? q_out : (which==1 ? k_out : v_out);
                    int bb = m>>11, t = m&(TT-1);
                    dst[(((size_t)(bb*HH+hh)*TT + t)<<6) + d] = f2bf(v);
                } else if (MODE==1){
                    size_t idx = (size_t)m*Ndim + n;
                    CoutF[idx] = resid[idx] + v;
                } else {
                    size_t idx = (size_t)m*Ndim + n;
                    CoutH[idx] = f2bf(0.5f*v*(1.0f + erff(v*0.70710678118f)));
                }
            }
        }
    }
}

// ---------------- flash attention (causal), bf16 in/out ----------------
__global__ __launch_bounds__(256) void attn_kernel(
    const u16* __restrict__ Q, const u16* __restrict__ K, const u16* __restrict__ V,
    u16* __restrict__ O)
{
    __shared__ u16 Ks[64*64];      // [s][d]
    __shared__ u16 Vs[64*64];      // [d][s]  (transposed)
    __shared__ u16 Ps[4][16*64];   // per wave [q][s]
    const int tid = threadIdx.x, wave = tid>>6, lane = tid&63;
    const int quad = lane>>4, l16 = lane&15;
    const int qt = blockIdx.x, bh = blockIdx.y;
    const size_t base = (size_t)bh*TT*DD;
    const u16* Qb = Q + base;
    const u16* Kb = K + base;
    const u16* Vb = V + base;
    const int q0 = qt*64 + wave*16;

    bf16x8 qf[2];
    #pragma unroll
    for (int h2=0; h2<2; h2++)
        qf[h2] = *(const bf16x8*)&Qb[(size_t)(q0+l16)*DD + h2*32 + quad*8];

    const f32x4 zf = {0.f,0.f,0.f,0.f};
    f32x4 oacc[4] = {zf,zf,zf,zf};
    float mrow[4], lrow[4];
    #pragma unroll
    for (int r=0;r<4;r++){ mrow[r]=-1e30f; lrow[r]=0.f; }

    for (int kt=0; kt<=qt; kt++){
        __syncthreads();
        {
            const int s0 = kt*64;
            const float4* gk = (const float4*)(Kb + (size_t)s0*DD);
            float4* sk = (float4*)Ks;
            sk[tid]      = gk[tid];
            sk[tid+256]  = gk[tid+256];
            #pragma unroll
            for (int i=0;i<2;i++){
                int idx = tid + i*256;
                int s = idx>>3, d8 = (idx&7)*8;
                const u16* pv = Vb + (size_t)(s0+s)*DD + d8;
                #pragma unroll
                for (int j=0;j<8;j++) Vs[(d8+j)*64 + s] = pv[j];
            }
        }
        __syncthreads();

        float sc[4][4];
        #pragma unroll
        for (int st=0; st<4; st++){
            f32x4 a = zf;
            #pragma unroll
            for (int h2=0;h2<2;h2++){
                bf16x8 kf = *(const bf16x8*)&Ks[(st*16+l16)*64 + h2*32 + quad*8];
                a = __builtin_amdgcn_mfma_f32_16x16x32_bf16(qf[h2], kf, a, 0,0,0);
            }
            #pragma unroll
            for (int r=0;r<4;r++) sc[st][r] = a[r]*0.125f;
        }
        if (kt==qt){
            #pragma unroll
            for (int st=0; st<4; st++)
                #pragma unroll
                for (int r=0;r<4;r++){
                    int s = kt*64 + st*16 + l16;
                    int q = q0 + quad*4 + r;
                    if (s>q) sc[st][r] = -1e30f;
                }
        }
        float mx[4];
        #pragma unroll
        for (int r=0;r<4;r++) mx[r] = fmaxf(fmaxf(sc[0][r],sc[1][r]), fmaxf(sc[2][r],sc[3][r]));
        #pragma unroll
        for (int off=1; off<16; off<<=1)
            #pragma unroll
            for (int r=0;r<4;r++) mx[r] = fmaxf(mx[r], __shfl_xor(mx[r],off));
        float alpha[4], psum[4];
        #pragma unroll
        for (int r=0;r<4;r++){
            float mn = fmaxf(mrow[r], mx[r]);
            alpha[r] = __expf(mrow[r]-mn);
            mrow[r] = mn; psum[r]=0.f;
        }
        #pragma unroll
        for (int st=0; st<4; st++)
            #pragma unroll
            for (int r=0;r<4;r++){
                float p = __expf(sc[st][r]-mrow[r]);
                psum[r]+=p;
                Ps[wave][(quad*4+r)*64 + st*16 + l16] = f2bf(p);
            }
        #pragma unroll
        for (int off=1; off<16; off<<=1)
            #pragma unroll
            for (int r=0;r<4;r++) psum[r] += __shfl_xor(psum[r],off);
        #pragma unroll
        for (int r=0;r<4;r++) lrow[r] = alpha[r]*lrow[r] + psum[r];
        #pragma unroll
        for (int dt=0; dt<4; dt++)
            #pragma unroll
            for (int r=0;r<4;r++) oacc[dt][r] *= alpha[r];

        bf16x8 pf[2];
        #pragma unroll
        for (int h2=0;h2<2;h2++)
            pf[h2] = *(const bf16x8*)&Ps[wave][l16*64 + h2*32 + quad*8];
        #pragma unroll
        for (int dt=0; dt<4; dt++){
            #pragma unroll
            for (int h2=0;h2<2;h2++){
                bf16x8 vf = *(const bf16x8*)&Vs[(dt*16+l16)*64 + h2*32 + quad*8];
                oacc[dt] = __builtin_amdgcn_mfma_f32_16x16x32_bf16(pf[h2], vf, oacc[dt], 0,0,0);
            }
        }
    }
    const int bb = bh>>4, hh = bh&15;
    #pragma unroll
    for (int dt=0; dt<4; dt++)
        #pragma unroll
        for (int r=0;r<4;r++){
            int t = qt*64 + wave*16 + quad*4 + r;
            float o = oacc[dt][r] / lrow[r];
            O[(size_t)(bb*TT + t)*EE + hh*64 + dt*16 + l16] = f2bf(o);
        }
}

extern "C" void kernel_launch(void* const* d_in, const int* in_sizes, int n_in,
                              void* d_out, int out_size, void* d_ws, size_t ws_size,
                              hipStream_t stream)
{
    (void)in_sizes; (void)n_in; (void)out_size; (void)ws_size;
    const int*   ids  = (const int*)d_in[0];
    const float* wte  = (const float*)d_in[1];
    const float* wpe  = (const float*)d_in[2];
    const float* wq   = (const float*)d_in[3];
    const float* wk   = (const float*)d_in[4];
    const float* wv   = (const float*)d_in[5];
    const float* bq   = (const float*)d_in[6];
    const float* bk   = (const float*)d_in[7];
    const float* bv   = (const float*)d_in[8];
    const float* wproj= (const float*)d_in[9];
    const float* bproj= (const float*)d_in[10];
    const float* ln1g = (const float*)d_in[11];
    const float* ln1b = (const float*)d_in[12];
    const float* ln2g = (const float*)d_in[13];
    const float* ln2b = (const float*)d_in[14];
    const float* wfc  = (const float*)d_in[15];
    const float* bfc  = (const float*)d_in[16];
    const float* wout = (const float*)d_in[17];
    const float* bout = (const float*)d_in[18];

    const size_t MTOK = (size_t)MM*EE;       // 8M elems
    char* p = (char*)d_ws;
    float* x    = (float*)p;  p += MTOK*sizeof(float);       // residual stream (f32)
    u16*  h     = (u16*)p;    p += MTOK*sizeof(u16);         // LN out (bf16)
    u16*  Qb    = (u16*)p;    p += MTOK*sizeof(u16);
    u16*  Kb    = (u16*)p;    p += MTOK*sizeof(u16);
    u16*  Vb    = (u16*)p;    p += MTOK*sizeof(u16);
    u16*  Ob    = (u16*)p;    p += MTOK*sizeof(u16);
    u16*  fcact = Qb;                                         // overlay: QKV+O dead by then (64MB)
    u16*  WqkvT = (u16*)p;    p += (size_t)3072*1024*sizeof(u16);
    float* biasq= (float*)p;  p += 3072*sizeof(float);
    u16*  wprojT= (u16*)p;    p += (size_t)1024*1024*sizeof(u16);
    u16*  wfcT  = (u16*)p;    p += (size_t)4096*1024*sizeof(u16);
    u16*  woutT = (u16*)p;    p += (size_t)1024*4096*sizeof(u16);
    float* out  = (float*)d_out;

    repack_qkv_tiled<<<dim3(2,32,48),dim3(32,8),0,stream>>>(wq,wk,wv,WqkvT);
    copy_bias_qkv<<<12,256,0,stream>>>(bq,bk,bv,biasq);
    transpose_tile<<<dim3(32,32), dim3(32,8),0,stream>>>(wproj, wprojT, 1024, 1024);
    transpose_tile<<<dim3(128,32),dim3(32,8),0,stream>>>(wfc,   wfcT,   4096, 1024);
    transpose_tile<<<dim3(32,128),dim3(32,8),0,stream>>>(wout,  woutT,  1024, 4096);
    embed_ln1<<<MM,256,0,stream>>>(ids, wte, wpe, ln1g, ln1b, x, h);
    gemm_bt<0><<<dim3(64,24),256,0,stream>>>(h, WqkvT, biasq, nullptr,nullptr,nullptr, Qb,Kb,Vb, 3072, 1024);
    attn_kernel<<<dim3(TT/64, BB*HH),256,0,stream>>>(Qb,Kb,Vb,Ob);
    gemm_bt<1><<<dim3(64,8),256,0,stream>>>(Ob, wprojT, bproj, x, x, nullptr, nullptr,nullptr,nullptr, 1024, 1024);
    ln_fwd<<<MM,256,0,stream>>>(x, ln2g, ln2b, h);
    gemm_bt<2><<<dim3(64,32),256,0,stream>>>(h, wfcT, bfc, nullptr,nullptr, fcact, nullptr,nullptr,nullptr, 4096, 1024);
    gemm_bt<1><<<dim3(64,8),256,0,stream>>>(fcact, woutT, bout, out, x, nullptr, nullptr,nullptr,nullptr, 1024, 4096);
}

// Round 3
// 846.894 us; speedup vs baseline: 1.2187x; 1.2187x over previous
//
#include <hip/hip_runtime.h>
#include <math.h>

#define BB 4
#define TT 2048
#define EE 1024
#define HH 16
#define DD 64
#define MM (BB*TT)   // 8192 tokens

typedef unsigned short u16;
typedef __bf16 bf16x8 __attribute__((ext_vector_type(8)));
typedef float  f32x4  __attribute__((ext_vector_type(4)));

__device__ inline float bf2f(u16 u){ union{unsigned int i; float f;} v; v.i=((unsigned int)u)<<16; return v.f; }
__device__ inline u16 f2bf(float f){ union{float f; unsigned int i;} v; v.f=f; return (u16)((v.i + 0x7fffu + ((v.i>>16)&1u))>>16); }

__device__ inline void gload_lds16(const void* g, void* l){
  __builtin_amdgcn_global_load_lds((__attribute__((address_space(1))) void*)g,
                                   (__attribute__((address_space(3))) void*)l, 16, 0, 0);
}

// ---------------- tiled transpose f32 -> bf16: W[K][N] -> WT[N][K] ----------------
__global__ __launch_bounds__(256) void transpose_tile(
    const float* __restrict__ W, u16* __restrict__ WT, int N, int K)
{
    __shared__ float t[32][33];
    const int n0 = blockIdx.x*32, k0 = blockIdx.y*32;
    const int tx = threadIdx.x, ty = threadIdx.y;   // 32 x 8
    #pragma unroll
    for (int j=0;j<4;j++)
        t[ty + j*8][tx] = W[(size_t)(k0 + ty + j*8)*N + n0 + tx];
    __syncthreads();
    #pragma unroll
    for (int j=0;j<4;j++)
        WT[(size_t)(n0 + ty + j*8)*K + k0 + tx] = f2bf(t[tx][ty + j*8]);
}

// ---------------- bf16 transpose V[bh][t][d] -> VT[bh][d][t] ----------------
__global__ __launch_bounds__(256) void transpose_v(
    const u16* __restrict__ V, u16* __restrict__ VT)
{
    __shared__ u16 t[32][34];
    const int bh = blockIdx.z;
    const int t0 = blockIdx.x*32;
    const int d0 = blockIdx.y*32;
    const int tx = threadIdx.x, ty = threadIdx.y;   // 32 x 8
    const u16* Vb = V + (size_t)bh*TT*DD;
    u16* VTb = VT + (size_t)bh*TT*DD;
    #pragma unroll
    for (int j=0;j<4;j++)
        t[ty+j*8][tx] = Vb[(size_t)(t0+ty+j*8)*DD + d0+tx];
    __syncthreads();
    #pragma unroll
    for (int j=0;j<4;j++)
        VTb[(size_t)(d0+ty+j*8)*TT + t0+tx] = t[tx][ty+j*8];
}

// ---------------- QKV repack f32 -> bf16 ----------------
__global__ __launch_bounds__(256) void repack_qkv_tiled(
    const float* __restrict__ wq, const float* __restrict__ wk, const float* __restrict__ wv,
    u16* __restrict__ WT)
{
    __shared__ float t[32][33];
    const int z = blockIdx.z, which = z>>4, hh = z&15;
    const int d0 = blockIdx.x*32, c0 = blockIdx.y*32;
    const int tx = threadIdx.x, ty = threadIdx.y;
    const float* w = which==0 ? wq : (which==1 ? wk : wv);
    #pragma unroll
    for (int j=0;j<4;j++)
        t[ty + j*8][tx] = w[((size_t)hh*EE + c0 + ty + j*8)*DD + d0 + tx];
    __syncthreads();
    #pragma unroll
    for (int j=0;j<4;j++)
        WT[(size_t)(which*1024 + hh*64 + d0 + ty + j*8)*1024 + c0 + tx] = f2bf(t[tx][ty + j*8]);
}

__global__ __launch_bounds__(256) void copy_bias_qkv(
    const float* __restrict__ bq, const float* __restrict__ bk, const float* __restrict__ bv,
    float* __restrict__ bias)
{
    int i = blockIdx.x*256 + threadIdx.x;   // < 3072
    const float* b = i<1024 ? bq : (i<2048 ? bk : bv);
    bias[i] = b[i & 1023];
}

// ---------------- embed + LN1 ----------------
__global__ __launch_bounds__(256) void embed_ln1(
    const int* __restrict__ ids, const float* __restrict__ wte, const float* __restrict__ wpe,
    const float* __restrict__ g, const float* __restrict__ b,
    float* __restrict__ x_out, u16* __restrict__ h_out)
{
    const int token = blockIdx.x;
    const int t = token & (TT-1);
    const int id = ids[token];
    const int tid = threadIdx.x;
    float vals[4]; float s=0.f, s2=0.f;
    #pragma unroll
    for (int i=0;i<4;i++){
        int e = tid + i*256;
        float v = wte[(size_t)id*EE + e] + wpe[(size_t)t*EE + e];
        vals[i]=v; s+=v; s2+=v*v;
    }
    for (int off=32; off>=1; off>>=1){ s += __shfl_xor(s,off); s2 += __shfl_xor(s2,off); }
    __shared__ float red[8];
    int wave=tid>>6, lane=tid&63;
    if (lane==0){ red[wave]=s; red[4+wave]=s2; }
    __syncthreads();
    s = red[0]+red[1]+red[2]+red[3];
    s2 = red[4]+red[5]+red[6]+red[7];
    float mu = s*(1.f/EE);
    float var = s2*(1.f/EE) - mu*mu;
    float rstd = rsqrtf(var + 1e-5f);
    #pragma unroll
    for (int i=0;i<4;i++){
        int e = tid + i*256; float v = vals[i];
        x_out[(size_t)token*EE + e] = v;
        h_out[(size_t)token*EE + e] = f2bf((v-mu)*rstd*g[e] + b[e]);
    }
}

// ---------------- LN2 ----------------
__global__ __launch_bounds__(256) void ln_fwd(
    const float* __restrict__ xin, const float* __restrict__ g, const float* __restrict__ b,
    u16* __restrict__ hout)
{
    const int token = blockIdx.x;
    const int tid = threadIdx.x;
    float vals[4]; float s=0.f, s2=0.f;
    #pragma unroll
    for (int i=0;i<4;i++){
        int e = tid + i*256;
        float v = xin[(size_t)token*EE + e];
        vals[i]=v; s+=v; s2+=v*v;
    }
    for (int off=32; off>=1; off>>=1){ s += __shfl_xor(s,off); s2 += __shfl_xor(s2,off); }
    __shared__ float red[8];
    int wave=tid>>6, lane=tid&63;
    if (lane==0){ red[wave]=s; red[4+wave]=s2; }
    __syncthreads();
    s = red[0]+red[1]+red[2]+red[3];
    s2 = red[4]+red[5]+red[6]+red[7];
    float mu = s*(1.f/EE);
    float var = s2*(1.f/EE) - mu*mu;
    float rstd = rsqrtf(var + 1e-5f);
    #pragma unroll
    for (int i=0;i<4;i++){
        int e = tid + i*256; float v = vals[i];
        hout[(size_t)token*EE + e] = f2bf((v-mu)*rstd*g[e] + b[e]);
    }
}

// ---------------- GEMM: C = A[M,K](bf16) * BT[N,K]^T(bf16) + bias(f32) ----------------
template<int MODE>
__global__ __launch_bounds__(256) void gemm_bt(
    const u16* __restrict__ A, const u16* __restrict__ BT, const float* __restrict__ bias,
    float* CoutF, const float* resid, u16* __restrict__ CoutH,
    u16* __restrict__ q_out, u16* __restrict__ k_out, u16* __restrict__ v_out,
    int Ndim, int Kdim)
{
    __shared__ u16 As[128*32];
    __shared__ u16 Bs[128*32];
    const int tid = threadIdx.x, wave = tid>>6, lane = tid&63;
    const int quad = lane>>4, l16 = lane&15;
    const int m0 = blockIdx.x<<7, n0 = blockIdx.y<<7;
    const int wm = (wave>>1)<<6, wn = (wave&1)<<6;
    const f32x4 zf = {0.f,0.f,0.f,0.f};
    f32x4 acc[4][4];
    #pragma unroll
    for (int i=0;i<4;i++)
        #pragma unroll
        for (int j=0;j<4;j++) acc[i][j]=zf;

    const int rA = lane>>2;
    const int kA = (lane&3)*8;
    for (int k0=0; k0<Kdim; k0+=32){
        __syncthreads();
        #pragma unroll
        for (int i=0;i<2;i++){
            const int inst = wave*2+i;
            const int row  = inst*16 + rA;
            gload_lds16(A  + (size_t)(m0+row)*Kdim + k0 + kA, &As[inst*512]);
            gload_lds16(BT + (size_t)(n0+row)*Kdim + k0 + kA, &Bs[inst*512]);
        }
        __syncthreads();
        bf16x8 af[4], bfr[4];
        #pragma unroll
        for (int mt=0;mt<4;mt++) af[mt]  = *(const bf16x8*)&As[(wm + mt*16 + l16)*32 + quad*8];
        #pragma unroll
        for (int nt=0;nt<4;nt++) bfr[nt] = *(const bf16x8*)&Bs[(wn + nt*16 + l16)*32 + quad*8];
        #pragma unroll
        for (int mt=0;mt<4;mt++)
            #pragma unroll
            for (int nt=0;nt<4;nt++)
                acc[mt][nt] = __builtin_amdgcn_mfma_f32_16x16x32_bf16(af[mt], bfr[nt], acc[mt][nt], 0, 0, 0);
    }
    #pragma unroll
    for (int mt=0;mt<4;mt++){
        #pragma unroll
        for (int nt=0;nt<4;nt++){
            #pragma unroll
            for (int r=0;r<4;r++){
                int m = m0 + wm + mt*16 + quad*4 + r;
                int n = n0 + wn + nt*16 + l16;
                float v = acc[mt][nt][r] + bias[n];
                if (MODE==0){
                    int which = n>>10, hd = n&1023, hh = hd>>6, d = hd&63;
                    u16* dst = which==0 ? q_out : (which==1 ? k_out : v_out);
                    int bb = m>>11, t = m&(TT-1);
                    dst[(((size_t)(bb*HH+hh)*TT + t)<<6) + d] = f2bf(v);
                } else if (MODE==1){
                    size_t idx = (size_t)m*Ndim + n;
                    CoutF[idx] = resid[idx] + v;
                } else {
                    size_t idx = (size_t)m*Ndim + n;
                    CoutH[idx] = f2bf(0.5f*v*(1.0f + erff(v*0.70710678118f)));
                }
            }
        }
    }
}

// ---------------- flash attention v2 (causal), swizzled LDS, no-rescale softmax ----
// grid (T/128, B*H), 256 threads. Wave handles 32 q rows (2 m-tiles of 16).
// Swizzle: chunk (row, jc) of 8 u16 lives at row*64 + (jc ^ (row&7))*8.
__global__ __launch_bounds__(256) void attn_kernel(
    const u16* __restrict__ Q, const u16* __restrict__ K, const u16* __restrict__ VT,
    u16* __restrict__ O)
{
    __shared__ u16 Ks[64*64];      // swizzled [s][k]
    __shared__ u16 Vs[64*64];      // swizzled [d][s]  (from VT)
    __shared__ u16 Ps[4*32*64];    // per-wave swizzled [ql][s]
    const int tid = threadIdx.x, wave = tid>>6, lane = tid&63;
    const int quad = lane>>4, l16 = lane&15;
    const int qt0 = blockIdx.x*128, bh = blockIdx.y;
    const size_t base = (size_t)bh*TT*DD;
    const u16* Qb = Q + base;
    const u16* Kb = K + base;
    const u16* VTb = VT + base;    // [d][t]
    const int q0 = qt0 + wave*32;

    bf16x8 qf[2][2];
    #pragma unroll
    for (int m=0;m<2;m++)
        #pragma unroll
        for (int h2=0;h2<2;h2++)
            qf[m][h2] = *(const bf16x8*)&Qb[(size_t)(q0+m*16+l16)*DD + h2*32 + quad*8];

    const f32x4 zf = {0.f,0.f,0.f,0.f};
    f32x4 oacc[2][4];
    float lsum[2][4];
    #pragma unroll
    for (int m=0;m<2;m++){
        #pragma unroll
        for (int dt=0;dt<4;dt++) oacc[m][dt]=zf;
        #pragma unroll
        for (int r=0;r<4;r++) lsum[m][r]=0.f;
    }

    const int ktEnd = (q0+31)>>6;        // last tile this wave contributes to
    const int ktMax = (qt0+127)>>6;      // block loop bound (inclusive)

    // staging chunk assignment (per wave, 2 rounds for K and 2 for V)
    const int c0 = wave*64 + lane, c1 = 256 + wave*64 + lane;
    const int r0 = c0>>3, j0 = (c0&7) ^ (r0&7);
    const int r1 = c1>>3, j1 = (c1&7) ^ (r1&7);

    for (int kt=0; kt<=ktMax; kt++){
        __syncthreads();
        {
            const int s0 = kt*64;
            gload_lds16(Kb  + (size_t)(s0+r0)*DD + j0*8, &Ks[wave*512]);
            gload_lds16(Kb  + (size_t)(s0+r1)*DD + j1*8, &Ks[(4+wave)*512]);
            gload_lds16(VTb + (size_t)r0*TT + s0 + j0*8, &Vs[wave*512]);
            gload_lds16(VTb + (size_t)r1*TT + s0 + j1*8, &Vs[(4+wave)*512]);
        }
        __syncthreads();
        if (kt > ktEnd) continue;

        // ---- QK^T: a[m][st], B-frags (K rows) shared across m ----
        f32x4 a[2][4];
        #pragma unroll
        for (int m=0;m<2;m++)
            #pragma unroll
            for (int st=0;st<4;st++) a[m][st]=zf;
        #pragma unroll
        for (int h2=0;h2<2;h2++){
            #pragma unroll
            for (int st=0;st<4;st++){
                const int s = st*16 + l16;
                const int jc = h2*4 + quad;
                bf16x8 kf = *(const bf16x8*)&Ks[s*64 + (jc ^ (s&7))*8];
                #pragma unroll
                for (int m=0;m<2;m++)
                    a[m][st] = __builtin_amdgcn_mfma_f32_16x16x32_bf16(qf[m][h2], kf, a[m][st], 0,0,0);
            }
        }
        // ---- p = exp(sc) (no shift; clamp for safety), mask, store Ps ----
        #pragma unroll
        for (int m=0;m<2;m++){
            const int q0m = q0 + m*16;
            #pragma unroll
            for (int st=0;st<4;st++){
                #pragma unroll
                for (int r=0;r<4;r++){
                    const int qrow = q0m + quad*4 + r;
                    const int s = kt*64 + st*16 + l16;
                    float p = (s > qrow) ? 0.f
                            : exp2f(fminf(a[m][st][r]*0.1803369f, 40.f));
                    lsum[m][r] += p;
                    const int ql = m*16 + quad*4 + r;
                    const int sc3 = st*2 + (l16>>3);
                    Ps[wave*2048 + ql*64 + (sc3 ^ (ql&7))*8 + (l16&7)] = f2bf(p);
                }
            }
        }
        // ---- PV: O += P * V^T ----
        #pragma unroll
        for (int kh=0; kh<2; kh++){
            const int jc = kh*4 + quad;
            bf16x8 pf[2];
            #pragma unroll
            for (int m=0;m<2;m++){
                const int ql16 = m*16 + l16;
                pf[m] = *(const bf16x8*)&Ps[wave*2048 + ql16*64 + (jc ^ (ql16&7))*8];
            }
            #pragma unroll
            for (int dt=0; dt<4; dt++){
                const int d = dt*16 + l16;
                bf16x8 vf = *(const bf16x8*)&Vs[d*64 + (jc ^ (d&7))*8];
                #pragma unroll
                for (int m=0;m<2;m++)
                    oacc[m][dt] = __builtin_amdgcn_mfma_f32_16x16x32_bf16(pf[m], vf, oacc[m][dt], 0,0,0);
            }
        }
    }
    // final row-sum reduce over the 16 lanes of each quad group
    #pragma unroll
    for (int off=1; off<16; off<<=1)
        #pragma unroll
        for (int m=0;m<2;m++)
            #pragma unroll
            for (int r=0;r<4;r++)
                lsum[m][r] += __shfl_xor(lsum[m][r], off);

    const int bb = bh>>4, hh = bh&15;
    #pragma unroll
    for (int m=0;m<2;m++)
        #pragma unroll
        for (int dt=0;dt<4;dt++)
            #pragma unroll
            for (int r=0;r<4;r++){
                const int t = q0 + m*16 + quad*4 + r;
                const float o = oacc[m][dt][r] / lsum[m][r];
                O[(size_t)(bb*TT + t)*EE + hh*64 + dt*16 + l16] = f2bf(o);
            }
}

extern "C" void kernel_launch(void* const* d_in, const int* in_sizes, int n_in,
                              void* d_out, int out_size, void* d_ws, size_t ws_size,
                              hipStream_t stream)
{
    (void)in_sizes; (void)n_in; (void)out_size; (void)ws_size;
    const int*   ids  = (const int*)d_in[0];
    const float* wte  = (const float*)d_in[1];
    const float* wpe  = (const float*)d_in[2];
    const float* wq   = (const float*)d_in[3];
    const float* wk   = (const float*)d_in[4];
    const float* wv   = (const float*)d_in[5];
    const float* bq   = (const float*)d_in[6];
    const float* bk   = (const float*)d_in[7];
    const float* bv   = (const float*)d_in[8];
    const float* wproj= (const float*)d_in[9];
    const float* bproj= (const float*)d_in[10];
    const float* ln1g = (const float*)d_in[11];
    const float* ln1b = (const float*)d_in[12];
    const float* ln2g = (const float*)d_in[13];
    const float* ln2b = (const float*)d_in[14];
    const float* wfc  = (const float*)d_in[15];
    const float* bfc  = (const float*)d_in[16];
    const float* wout = (const float*)d_in[17];
    const float* bout = (const float*)d_in[18];

    const size_t MTOK = (size_t)MM*EE;       // 8M elems
    char* p = (char*)d_ws;
    float* x    = (float*)p;  p += MTOK*sizeof(float);
    u16*  h     = (u16*)p;    p += MTOK*sizeof(u16);
    u16*  Qb    = (u16*)p;    p += MTOK*sizeof(u16);
    u16*  Kb    = (u16*)p;    p += MTOK*sizeof(u16);
    u16*  Vb    = (u16*)p;    p += MTOK*sizeof(u16);
    u16*  Ob    = (u16*)p;    p += MTOK*sizeof(u16);
    u16*  fcact = Qb;                        // overlay: Q/K/V/O dead by MLP
    u16*  VTv   = h;                         // overlay: h dead between QKV gemm and LN2
    u16*  WqkvT = (u16*)p;    p += (size_t)3072*1024*sizeof(u16);
    float* biasq= (float*)p;  p += 3072*sizeof(float);
    u16*  wprojT= (u16*)p;    p += (size_t)1024*1024*sizeof(u16);
    u16*  wfcT  = (u16*)p;    p += (size_t)4096*1024*sizeof(u16);
    u16*  woutT = (u16*)p;    p += (size_t)1024*4096*sizeof(u16);
    float* out  = (float*)d_out;

    repack_qkv_tiled<<<dim3(2,32,48),dim3(32,8),0,stream>>>(wq,wk,wv,WqkvT);
    copy_bias_qkv<<<12,256,0,stream>>>(bq,bk,bv,biasq);
    transpose_tile<<<dim3(32,32), dim3(32,8),0,stream>>>(wproj, wprojT, 1024, 1024);
    transpose_tile<<<dim3(128,32),dim3(32,8),0,stream>>>(wfc,   wfcT,   4096, 1024);
    transpose_tile<<<dim3(32,128),dim3(32,8),0,stream>>>(wout,  woutT,  1024, 4096);
    embed_ln1<<<MM,256,0,stream>>>(ids, wte, wpe, ln1g, ln1b, x, h);
    gemm_bt<0><<<dim3(64,24),256,0,stream>>>(h, WqkvT, biasq, nullptr,nullptr,nullptr, Qb,Kb,Vb, 3072, 1024);
    transpose_v<<<dim3(64,2,64),dim3(32,8),0,stream>>>(Vb, VTv);
    attn_kernel<<<dim3(TT/128, BB*HH),256,0,stream>>>(Qb,Kb,VTv,Ob);
    gemm_bt<1><<<dim3(64,8),256,0,stream>>>(Ob, wprojT, bproj, x, x, nullptr, nullptr,nullptr,nullptr, 1024, 1024);
    ln_fwd<<<MM,256,0,stream>>>(x, ln2g, ln2b, h);
    gemm_bt<2><<<dim3(64,32),256,0,stream>>>(h, wfcT, bfc, nullptr,nullptr, fcact, nullptr,nullptr,nullptr, 4096, 1024);
    gemm_bt<1><<<dim3(64,8),256,0,stream>>>(fcact, woutT, bout, out, x, nullptr, nullptr,nullptr,nullptr, 1024, 4096);
}

// Round 4
// 757.721 us; speedup vs baseline: 1.3621x; 1.1177x over previous
//
#include <hip/hip_runtime.h>
#include <math.h>

#define BB 4
#define TT 2048
#define EE 1024
#define HH 16
#define DD 64
#define MM (BB*TT)   // 8192 tokens

typedef unsigned short u16;
typedef __bf16 bf16x8 __attribute__((ext_vector_type(8)));
typedef float  f32x4  __attribute__((ext_vector_type(4)));

__device__ inline float bf2f(u16 u){ union{unsigned int i; float f;} v; v.i=((unsigned int)u)<<16; return v.f; }
__device__ inline u16 f2bf(float f){ union{float f; unsigned int i;} v; v.f=f; return (u16)((v.i + 0x7fffu + ((v.i>>16)&1u))>>16); }
__device__ inline u16 f2bf_trunc(float f){ union{float f; unsigned int i;} v; v.f=f; return (u16)(v.i>>16); }

__device__ inline void gload_lds16(const void* g, void* l){
  __builtin_amdgcn_global_load_lds((__attribute__((address_space(1))) void*)g,
                                   (__attribute__((address_space(3))) void*)l, 16, 0, 0);
}

// ---------------- tiled transpose f32 -> bf16: W[K][N] -> WT[N][K] ----------------
__global__ __launch_bounds__(256) void transpose_tile(
    const float* __restrict__ W, u16* __restrict__ WT, int N, int K)
{
    __shared__ float t[32][33];
    const int n0 = blockIdx.x*32, k0 = blockIdx.y*32;
    const int tx = threadIdx.x, ty = threadIdx.y;   // 32 x 8
    #pragma unroll
    for (int j=0;j<4;j++)
        t[ty + j*8][tx] = W[(size_t)(k0 + ty + j*8)*N + n0 + tx];
    __syncthreads();
    #pragma unroll
    for (int j=0;j<4;j++)
        WT[(size_t)(n0 + ty + j*8)*K + k0 + tx] = f2bf(t[tx][ty + j*8]);
}

// ---------------- bf16 transpose V[bh][t][d] -> VT[bh][d][t] ----------------
__global__ __launch_bounds__(256) void transpose_v(
    const u16* __restrict__ V, u16* __restrict__ VT)
{
    __shared__ u16 t[32][34];
    const int bh = blockIdx.z;
    const int t0 = blockIdx.x*32;
    const int d0 = blockIdx.y*32;
    const int tx = threadIdx.x, ty = threadIdx.y;   // 32 x 8
    const u16* Vb = V + (size_t)bh*TT*DD;
    u16* VTb = VT + (size_t)bh*TT*DD;
    #pragma unroll
    for (int j=0;j<4;j++)
        t[ty+j*8][tx] = Vb[(size_t)(t0+ty+j*8)*DD + d0+tx];
    __syncthreads();
    #pragma unroll
    for (int j=0;j<4;j++)
        VTb[(size_t)(d0+ty+j*8)*TT + t0+tx] = t[tx][ty+j*8];
}

// ---------------- QKV repack f32 -> bf16 ----------------
__global__ __launch_bounds__(256) void repack_qkv_tiled(
    const float* __restrict__ wq, const float* __restrict__ wk, const float* __restrict__ wv,
    u16* __restrict__ WT)
{
    __shared__ float t[32][33];
    const int z = blockIdx.z, which = z>>4, hh = z&15;
    const int d0 = blockIdx.x*32, c0 = blockIdx.y*32;
    const int tx = threadIdx.x, ty = threadIdx.y;
    const float* w = which==0 ? wq : (which==1 ? wk : wv);
    #pragma unroll
    for (int j=0;j<4;j++)
        t[ty + j*8][tx] = w[((size_t)hh*EE + c0 + ty + j*8)*DD + d0 + tx];
    __syncthreads();
    #pragma unroll
    for (int j=0;j<4;j++)
        WT[(size_t)(which*1024 + hh*64 + d0 + ty + j*8)*1024 + c0 + tx] = f2bf(t[tx][ty + j*8]);
}

__global__ __launch_bounds__(256) void copy_bias_qkv(
    const float* __restrict__ bq, const float* __restrict__ bk, const float* __restrict__ bv,
    float* __restrict__ bias)
{
    int i = blockIdx.x*256 + threadIdx.x;   // < 3072
    const float* b = i<1024 ? bq : (i<2048 ? bk : bv);
    bias[i] = b[i & 1023];
}

// ---------------- embed + LN1 ----------------
__global__ __launch_bounds__(256) void embed_ln1(
    const int* __restrict__ ids, const float* __restrict__ wte, const float* __restrict__ wpe,
    const float* __restrict__ g, const float* __restrict__ b,
    float* __restrict__ x_out, u16* __restrict__ h_out)
{
    const int token = blockIdx.x;
    const int t = token & (TT-1);
    const int id = ids[token];
    const int tid = threadIdx.x;
    float vals[4]; float s=0.f, s2=0.f;
    #pragma unroll
    for (int i=0;i<4;i++){
        int e = tid + i*256;
        float v = wte[(size_t)id*EE + e] + wpe[(size_t)t*EE + e];
        vals[i]=v; s+=v; s2+=v*v;
    }
    for (int off=32; off>=1; off>>=1){ s += __shfl_xor(s,off); s2 += __shfl_xor(s2,off); }
    __shared__ float red[8];
    int wave=tid>>6, lane=tid&63;
    if (lane==0){ red[wave]=s; red[4+wave]=s2; }
    __syncthreads();
    s = red[0]+red[1]+red[2]+red[3];
    s2 = red[4]+red[5]+red[6]+red[7];
    float mu = s*(1.f/EE);
    float var = s2*(1.f/EE) - mu*mu;
    float rstd = rsqrtf(var + 1e-5f);
    #pragma unroll
    for (int i=0;i<4;i++){
        int e = tid + i*256; float v = vals[i];
        x_out[(size_t)token*EE + e] = v;
        h_out[(size_t)token*EE + e] = f2bf((v-mu)*rstd*g[e] + b[e]);
    }
}

// ---------------- LN2 ----------------
__global__ __launch_bounds__(256) void ln_fwd(
    const float* __restrict__ xin, const float* __restrict__ g, const float* __restrict__ b,
    u16* __restrict__ hout)
{
    const int token = blockIdx.x;
    const int tid = threadIdx.x;
    float vals[4]; float s=0.f, s2=0.f;
    #pragma unroll
    for (int i=0;i<4;i++){
        int e = tid + i*256;
        float v = xin[(size_t)token*EE + e];
        vals[i]=v; s+=v; s2+=v*v;
    }
    for (int off=32; off>=1; off>>=1){ s += __shfl_xor(s,off); s2 += __shfl_xor(s2,off); }
    __shared__ float red[8];
    int wave=tid>>6, lane=tid&63;
    if (lane==0){ red[wave]=s; red[4+wave]=s2; }
    __syncthreads();
    s = red[0]+red[1]+red[2]+red[3];
    s2 = red[4]+red[5]+red[6]+red[7];
    float mu = s*(1.f/EE);
    float var = s2*(1.f/EE) - mu*mu;
    float rstd = rsqrtf(var + 1e-5f);
    #pragma unroll
    for (int i=0;i<4;i++){
        int e = tid + i*256; float v = vals[i];
        hout[(size_t)token*EE + e] = f2bf((v-mu)*rstd*g[e] + b[e]);
    }
}

// ---------------- GEMM: C = A[M,K](bf16) * BT[N,K]^T(bf16) + bias(f32) ----------------
template<int MODE>
__global__ __launch_bounds__(256) void gemm_bt(
    const u16* __restrict__ A, const u16* __restrict__ BT, const float* __restrict__ bias,
    float* CoutF, const float* resid, u16* __restrict__ CoutH,
    u16* __restrict__ q_out, u16* __restrict__ k_out, u16* __restrict__ v_out,
    int Ndim, int Kdim)
{
    __shared__ u16 As[128*32];
    __shared__ u16 Bs[128*32];
    const int tid = threadIdx.x, wave = tid>>6, lane = tid&63;
    const int quad = lane>>4, l16 = lane&15;
    const int m0 = blockIdx.x<<7, n0 = blockIdx.y<<7;
    const int wm = (wave>>1)<<6, wn = (wave&1)<<6;
    const f32x4 zf = {0.f,0.f,0.f,0.f};
    f32x4 acc[4][4];
    #pragma unroll
    for (int i=0;i<4;i++)
        #pragma unroll
        for (int j=0;j<4;j++) acc[i][j]=zf;

    const int rA = lane>>2;
    const int kA = (lane&3)*8;
    for (int k0=0; k0<Kdim; k0+=32){
        __syncthreads();
        #pragma unroll
        for (int i=0;i<2;i++){
            const int inst = wave*2+i;
            const int row  = inst*16 + rA;
            gload_lds16(A  + (size_t)(m0+row)*Kdim + k0 + kA, &As[inst*512]);
            gload_lds16(BT + (size_t)(n0+row)*Kdim + k0 + kA, &Bs[inst*512]);
        }
        __syncthreads();
        bf16x8 af[4], bfr[4];
        #pragma unroll
        for (int mt=0;mt<4;mt++) af[mt]  = *(const bf16x8*)&As[(wm + mt*16 + l16)*32 + quad*8];
        #pragma unroll
        for (int nt=0;nt<4;nt++) bfr[nt] = *(const bf16x8*)&Bs[(wn + nt*16 + l16)*32 + quad*8];
        #pragma unroll
        for (int mt=0;mt<4;mt++)
            #pragma unroll
            for (int nt=0;nt<4;nt++)
                acc[mt][nt] = __builtin_amdgcn_mfma_f32_16x16x32_bf16(af[mt], bfr[nt], acc[mt][nt], 0, 0, 0);
    }
    #pragma unroll
    for (int mt=0;mt<4;mt++){
        #pragma unroll
        for (int nt=0;nt<4;nt++){
            #pragma unroll
            for (int r=0;r<4;r++){
                int m = m0 + wm + mt*16 + quad*4 + r;
                int n = n0 + wn + nt*16 + l16;
                float v = acc[mt][nt][r] + bias[n];
                if (MODE==0){
                    int which = n>>10, hd = n&1023, hh = hd>>6, d = hd&63;
                    u16* dst = which==0 ? q_out : (which==1 ? k_out : v_out);
                    int bb = m>>11, t = m&(TT-1);
                    dst[(((size_t)(bb*HH+hh)*TT + t)<<6) + d] = f2bf(v);
                } else if (MODE==1){
                    size_t idx = (size_t)m*Ndim + n;
                    CoutF[idx] = resid[idx] + v;
                } else {
                    size_t idx = (size_t)m*Ndim + n;
                    CoutH[idx] = f2bf(0.5f*v*(1.0f + erff(v*0.70710678118f)));
                }
            }
        }
    }
}

// ---------------- flash attention v3: causal-paired, balanced, swizzled ----------
// Flat grid 512. id%8 == bh%8 (XCD locality). Block does q-tiles {pair, 15-pair}
// of one bh; every block = 34 k-tile-units of work.
__device__ __forceinline__ void attn_proc_tile(
    int kt, int q0, int quad, int l16,
    const u16* Ks, const u16* Vs, u16* Psw,
    const bf16x8 (&qf)[2][2], f32x4 (&oacc)[2][4], float (&lsum)[2][4])
{
    if (kt > ((q0+31)>>6)) return;           // wave-uniform
    const f32x4 zf = {0.f,0.f,0.f,0.f};
    f32x4 a[2][4];
    #pragma unroll
    for (int m=0;m<2;m++)
        #pragma unroll
        for (int st=0;st<4;st++) a[m][st]=zf;
    #pragma unroll
    for (int h2=0;h2<2;h2++){
        #pragma unroll
        for (int st=0;st<4;st++){
            const int s = st*16 + l16;
            const int jc = h2*4 + quad;
            bf16x8 kf = *(const bf16x8*)&Ks[s*64 + (jc ^ (s&7))*8];
            #pragma unroll
            for (int m=0;m<2;m++)
                a[m][st] = __builtin_amdgcn_mfma_f32_16x16x32_bf16(qf[m][h2], kf, a[m][st], 0,0,0);
        }
    }
    const bool needMask = (kt*64 + 63 > q0);
    #pragma unroll
    for (int m=0;m<2;m++){
        const int q0m = q0 + m*16;
        #pragma unroll
        for (int st=0;st<4;st++){
            #pragma unroll
            for (int r=0;r<4;r++){
                float p = exp2f(fminf(a[m][st][r]*0.1803369f, 40.f));
                if (needMask){
                    const int qrow = q0m + quad*4 + r;
                    const int s = kt*64 + st*16 + l16;
                    if (s > qrow) p = 0.f;
                }
                lsum[m][r] += p;
                const int ql = m*16 + quad*4 + r;
                const int sc3 = st*2 + (l16>>3);
                Psw[ql*64 + (sc3 ^ (ql&7))*8 + (l16&7)] = f2bf_trunc(p);
            }
        }
    }
    #pragma unroll
    for (int kh=0; kh<2; kh++){
        const int jc = kh*4 + quad;
        bf16x8 pf[2];
        #pragma unroll
        for (int m=0;m<2;m++){
            const int ql16 = m*16 + l16;
            pf[m] = *(const bf16x8*)&Psw[ql16*64 + (jc ^ (ql16&7))*8];
        }
        #pragma unroll
        for (int dt=0; dt<4; dt++){
            const int d = dt*16 + l16;
            bf16x8 vf = *(const bf16x8*)&Vs[d*64 + (jc ^ (d&7))*8];
            #pragma unroll
            for (int m=0;m<2;m++)
                oacc[m][dt] = __builtin_amdgcn_mfma_f32_16x16x32_bf16(pf[m], vf, oacc[m][dt], 0,0,0);
        }
    }
}

__global__ __launch_bounds__(256,2) void attn_kernel(
    const u16* __restrict__ Q, const u16* __restrict__ K, const u16* __restrict__ VT,
    u16* __restrict__ O)
{
    __shared__ u16 Ks[64*64];
    __shared__ u16 Vs[64*64];
    __shared__ u16 Ps[4*2048];
    const int tid = threadIdx.x, wave = tid>>6, lane = tid&63;
    const int quad = lane>>4, l16 = lane&15;
    const int id = blockIdx.x;
    const int bh   = (id&7) | ((id>>6)<<3);
    const int pair = (id>>3)&7;
    const int qtA = pair, qtB = 15-pair;
    const size_t base = (size_t)bh*TT*DD;
    const u16* Qb = Q + base;
    const u16* Kb = K + base;
    const u16* VTb = VT + base;
    const int qA0 = qtA*128 + wave*32;
    const int qB0 = qtB*128 + wave*32;
    u16* Psw = &Ps[wave*2048];

    bf16x8 qfA[2][2], qfB[2][2];
    #pragma unroll
    for (int m=0;m<2;m++)
        #pragma unroll
        for (int h2=0;h2<2;h2++){
            qfA[m][h2] = *(const bf16x8*)&Qb[(size_t)(qA0+m*16+l16)*DD + h2*32 + quad*8];
            qfB[m][h2] = *(const bf16x8*)&Qb[(size_t)(qB0+m*16+l16)*DD + h2*32 + quad*8];
        }

    const f32x4 zf = {0.f,0.f,0.f,0.f};
    f32x4 oaccA[2][4], oaccB[2][4];
    float lsumA[2][4], lsumB[2][4];
    #pragma unroll
    for (int m=0;m<2;m++){
        #pragma unroll
        for (int dt=0;dt<4;dt++){ oaccA[m][dt]=zf; oaccB[m][dt]=zf; }
        #pragma unroll
        for (int r=0;r<4;r++){ lsumA[m][r]=0.f; lsumB[m][r]=0.f; }
    }

    const int ktMax = 31 - 2*pair;     // tile B's diagonal (>= tile A's range)

    const int c0 = wave*64 + lane, c1 = 256 + wave*64 + lane;
    const int r0 = c0>>3, j0 = (c0&7) ^ (r0&7);
    const int r1 = c1>>3, j1 = (c1&7) ^ (r1&7);

    for (int kt=0; kt<=ktMax; kt++){
        __syncthreads();
        {
            const int s0 = kt*64;
            gload_lds16(Kb  + (size_t)(s0+r0)*DD + j0*8, &Ks[wave*512]);
            gload_lds16(Kb  + (size_t)(s0+r1)*DD + j1*8, &Ks[(4+wave)*512]);
            gload_lds16(VTb + (size_t)r0*TT + s0 + j0*8, &Vs[wave*512]);
            gload_lds16(VTb + (size_t)r1*TT + s0 + j1*8, &Vs[(4+wave)*512]);
        }
        __syncthreads();
        attn_proc_tile(kt, qB0, quad, l16, Ks, Vs, Psw, qfB, oaccB, lsumB);
        attn_proc_tile(kt, qA0, quad, l16, Ks, Vs, Psw, qfA, oaccA, lsumA);
    }

    #pragma unroll
    for (int off=1; off<16; off<<=1)
        #pragma unroll
        for (int m=0;m<2;m++)
            #pragma unroll
            for (int r=0;r<4;r++){
                lsumA[m][r] += __shfl_xor(lsumA[m][r], off);
                lsumB[m][r] += __shfl_xor(lsumB[m][r], off);
            }

    const int bb = bh>>4, hh = bh&15;
    #pragma unroll
    for (int m=0;m<2;m++)
        #pragma unroll
        for (int dt=0;dt<4;dt++)
            #pragma unroll
            for (int r=0;r<4;r++){
                int t = qA0 + m*16 + quad*4 + r;
                O[(size_t)(bb*TT + t)*EE + hh*64 + dt*16 + l16] = f2bf(oaccA[m][dt][r] / lsumA[m][r]);
                t = qB0 + m*16 + quad*4 + r;
                O[(size_t)(bb*TT + t)*EE + hh*64 + dt*16 + l16] = f2bf(oaccB[m][dt][r] / lsumB[m][r]);
            }
}

extern "C" void kernel_launch(void* const* d_in, const int* in_sizes, int n_in,
                              void* d_out, int out_size, void* d_ws, size_t ws_size,
                              hipStream_t stream)
{
    (void)in_sizes; (void)n_in; (void)out_size; (void)ws_size;
    const int*   ids  = (const int*)d_in[0];
    const float* wte  = (const float*)d_in[1];
    const float* wpe  = (const float*)d_in[2];
    const float* wq   = (const float*)d_in[3];
    const float* wk   = (const float*)d_in[4];
    const float* wv   = (const float*)d_in[5];
    const float* bq   = (const float*)d_in[6];
    const float* bk   = (const float*)d_in[7];
    const float* bv   = (const float*)d_in[8];
    const float* wproj= (const float*)d_in[9];
    const float* bproj= (const float*)d_in[10];
    const float* ln1g = (const float*)d_in[11];
    const float* ln1b = (const float*)d_in[12];
    const float* ln2g = (const float*)d_in[13];
    const float* ln2b = (const float*)d_in[14];
    const float* wfc  = (const float*)d_in[15];
    const float* bfc  = (const float*)d_in[16];
    const float* wout = (const float*)d_in[17];
    const float* bout = (const float*)d_in[18];

    const size_t MTOK = (size_t)MM*EE;       // 8M elems
    char* p = (char*)d_ws;
    float* x    = (float*)p;  p += MTOK*sizeof(float);
    u16*  h     = (u16*)p;    p += MTOK*sizeof(u16);
    u16*  Qb    = (u16*)p;    p += MTOK*sizeof(u16);
    u16*  Kb    = (u16*)p;    p += MTOK*sizeof(u16);
    u16*  Vb    = (u16*)p;    p += MTOK*sizeof(u16);
    u16*  Ob    = (u16*)p;    p += MTOK*sizeof(u16);
    u16*  fcact = Qb;                        // overlay: Q/K/V/O dead by MLP
    u16*  VTv   = h;                         // overlay: h dead between QKV gemm and LN2
    u16*  WqkvT = (u16*)p;    p += (size_t)3072*1024*sizeof(u16);
    float* biasq= (float*)p;  p += 3072*sizeof(float);
    u16*  wprojT= (u16*)p;    p += (size_t)1024*1024*sizeof(u16);
    u16*  wfcT  = (u16*)p;    p += (size_t)4096*1024*sizeof(u16);
    u16*  woutT = (u16*)p;    p += (size_t)1024*4096*sizeof(u16);
    float* out  = (float*)d_out;

    repack_qkv_tiled<<<dim3(2,32,48),dim3(32,8),0,stream>>>(wq,wk,wv,WqkvT);
    copy_bias_qkv<<<12,256,0,stream>>>(bq,bk,bv,biasq);
    transpose_tile<<<dim3(32,32), dim3(32,8),0,stream>>>(wproj, wprojT, 1024, 1024);
    transpose_tile<<<dim3(128,32),dim3(32,8),0,stream>>>(wfc,   wfcT,   4096, 1024);
    transpose_tile<<<dim3(32,128),dim3(32,8),0,stream>>>(wout,  woutT,  1024, 4096);
    embed_ln1<<<MM,256,0,stream>>>(ids, wte, wpe, ln1g, ln1b, x, h);
    gemm_bt<0><<<dim3(64,24),256,0,stream>>>(h, WqkvT, biasq, nullptr,nullptr,nullptr, Qb,Kb,Vb, 3072, 1024);
    transpose_v<<<dim3(64,2,64),dim3(32,8),0,stream>>>(Vb, VTv);
    attn_kernel<<<512,256,0,stream>>>(Qb,Kb,VTv,Ob);
    gemm_bt<1><<<dim3(64,8),256,0,stream>>>(Ob, wprojT, bproj, x, x, nullptr, nullptr,nullptr,nullptr, 1024, 1024);
    ln_fwd<<<MM,256,0,stream>>>(x, ln2g, ln2b, h);
    gemm_bt<2><<<dim3(64,32),256,0,stream>>>(h, wfcT, bfc, nullptr,nullptr, fcact, nullptr,nullptr,nullptr, 4096, 1024);
    gemm_bt<1><<<dim3(64,8),256,0,stream>>>(fcact, woutT, bout, out, x, nullptr, nullptr,nullptr,nullptr, 1024, 4096);
}